// Round 10
// baseline (146.464 us; speedup 1.0000x reference)
//
#include <hip/hip_runtime.h>
#include <hip/hip_bf16.h>

typedef __bf16 bf16x8 __attribute__((ext_vector_type(8)));
typedef float f32x4 __attribute__((ext_vector_type(4)));

#define N_NODE 50000
#define KPATH 8
#define LPATH 6
#define DNODE 64
#define DPATH 128
#define KDIM 320                 // DNODE*(LPATH-1)
#define N_EDGE 1600000
#define NPAIR (N_NODE * KPATH)   // 400000
#define NEW (NPAIR * (LPATH - 1))// 2,000,000 path-edge slots
#define M_BLK 64
#define NBLK (NPAIR / M_BLK)     // 6250
#define ROW_BYTES 640            // 320 bf16 per row, swizzled
#define WF_BYTES 81920
#define FEATB_BYTES (N_NODE * DNODE * 2)
#define EWB_BYTES (N_EDGE * 2)
#define EWD_BYTES (NEW * 2)

// fused-prep block ranges
#define WF_BLKS   160                      // 40960 wf elements
#define FEAT_BLKS 1563                     // 400000 x 8-elem converts
#define WGT_BLKS  782                      // 200000 x 8-elem converts
#define PREP_BLKS (WF_BLKS + FEAT_BLKS + WGT_BLKS)

// XOR-swizzle: 16B unit moved within its 128B group by row. 640 = 5*128 so
// the XOR (max 112) never crosses a row boundary.
__device__ __forceinline__ int swz(int row, int bytecol) {
    return row * ROW_BYTES + (bytecol ^ ((row & 7) << 4));
}

// One launch: W->wf fragment swizzle, feat->bf16, weight->bf16.
__global__ void fused_prep(const float* __restrict__ W, __bf16* __restrict__ wf,
                           const float* __restrict__ feat, __bf16* __restrict__ featb,
                           const float* __restrict__ weight, __bf16* __restrict__ ewb) {
    int b = blockIdx.x;
    if (b < WF_BLKS) {
        int t = b * 256 + threadIdx.x;
        if (t >= 8 * 10 * 64 * 8) return;
        int j    = t & 7;
        int lane = (t >> 3) & 63;
        int ks   = (t >> 9) % 10;
        int nt   = t / 5120;
        int k = ks * 32 + (lane >> 4) * 8 + j;
        int n = nt * 16 + (lane & 15);
        wf[t] = (__bf16)W[n * KDIM + k];
    } else if (b < WF_BLKS + FEAT_BLKS) {
        int t = (b - WF_BLKS) * 256 + threadIdx.x;
        if (t >= N_NODE * DNODE / 8) return;
        float4 a = ((const float4*)feat)[t * 2];
        float4 c = ((const float4*)feat)[t * 2 + 1];
        union { bf16x8 v; __bf16 e[8]; } u;
        u.e[0] = (__bf16)a.x; u.e[1] = (__bf16)a.y; u.e[2] = (__bf16)a.z; u.e[3] = (__bf16)a.w;
        u.e[4] = (__bf16)c.x; u.e[5] = (__bf16)c.y; u.e[6] = (__bf16)c.z; u.e[7] = (__bf16)c.w;
        ((bf16x8*)featb)[t] = u.v;
    } else {
        int t = (b - WF_BLKS - FEAT_BLKS) * 256 + threadIdx.x;
        if (t >= N_EDGE / 8) return;
        float4 a = ((const float4*)weight)[t * 2];
        float4 c = ((const float4*)weight)[t * 2 + 1];
        union { bf16x8 v; __bf16 e[8]; } u;
        u.e[0] = (__bf16)a.x; u.e[1] = (__bf16)a.y; u.e[2] = (__bf16)a.z; u.e[3] = (__bf16)a.w;
        u.e[4] = (__bf16)c.x; u.e[5] = (__bf16)c.y; u.e[6] = (__bf16)c.z; u.e[7] = (__bf16)c.w;
        ((bf16x8*)ewb)[t] = u.v;
    }
}

// Pre-gather edge weights per path slot: ewd[t] = ewb[eids[t]].
// ewb is 3.2 MB bf16 -> fits per-XCD L2, so this random gather is cheap here
// and removes 2M random scalar loads from the hot kernel.
__global__ void ew_prep(const __bf16* __restrict__ ewb, const int* __restrict__ eids,
                        __bf16* __restrict__ ewd, int n) {
    int t = blockIdx.x * 256 + threadIdx.x;
    if (t >= n) return;
    int ev = __builtin_nontemporal_load(eids + t);
    ewd[t] = ewb[ev];
}

// MODE: 1 = feat bf16 + pre-gathered ew bf16 ; 0 = all-f32 inline fallback
template <int MODE>
__global__ __launch_bounds__(256, 4) void path_gemm(
    const void*  __restrict__ featv,
    const void*  __restrict__ wsrc,     // MODE1: ewd (dense bf16); MODE0: weight f32
    const int*   __restrict__ paths,
    const int*   __restrict__ eids,
    const __bf16* __restrict__ wf,
    float* __restrict__ out)
{
    __shared__ bf16x8 AsVec[M_BLK * ROW_BYTES / 16];   // 40,960 B -> 4 blocks/CU
    char* asb = (char*)AsVec;

    const int  t  = threadIdx.x;
    const long p0 = (long)blockIdx.x * M_BLK;
    const int wave = t >> 6;
    const int lane = t & 63;

    // ---- B fragments: load ONCE per block into VGPRs (kills the wf re-read).
    //      Issued first so the L2-hit latency overlaps the gathers below.
    bf16x8 breg[10][2];
#pragma unroll
    for (int ks = 0; ks < 10; ++ks)
#pragma unroll
        for (int nt = 0; nt < 2; ++nt)
            breg[ks][nt] = *(const bf16x8*)(wf + (((wave * 2 + nt) * 10 + ks) * 64 + lane) * 8);

    // ---------------- stage A tile: gather + combine -> bf16 LDS ----------
    // Two passes of the proven 32-row lane-split shape (rows 0-31, 32-63).
    {
        const int  s  = t & 7;           // 16B slice
        const int  d0 = s * 8;
        const int  lr = (t >> 3) & 7;    // row-local index within this wave

#pragma unroll
        for (int pass = 0; pass < 2; ++pass) {
            const int  r = pass * 32 + (t >> 3);     // row 0..63
            const long p = p0 + r;

            // Lane-split scalar loads, broadcast to the row's 8 lanes.
            int pv = 0;
            if (s < LPATH) pv = __builtin_nontemporal_load(paths + p * LPATH + s);
            float wv = 0.f;
            if (s < LPATH - 1) {
                if (MODE) {
                    wv = (float)__builtin_nontemporal_load(
                        (const __bf16*)wsrc + p * (LPATH - 1) + s);
                } else {
                    int ev = __builtin_nontemporal_load(eids + p * (LPATH - 1) + s);
                    wv = ((const float*)wsrc)[ev];
                }
            }

            int idx[LPATH];
#pragma unroll
            for (int l = 0; l < LPATH; ++l) idx[l] = __shfl(pv, lr * 8 + l, 64);
            float ew[LPATH - 1];
#pragma unroll
            for (int l = 0; l < LPATH - 1; ++l) ew[l] = __shfl(wv, lr * 8 + l, 64);

            // Issue ALL 6 row-gathers unconditionally (clamped addr + mask)
            // so the misses overlap instead of serializing 6-deep.
            float msk[LPATH];
            union { bf16x8 v; __bf16 e[8]; } raw[LPATH];
            float4 rawf[LPATH][2];
#pragma unroll
            for (int l = 0; l < LPATH; ++l) {
                const int id = idx[l];
                msk[l] = (id < N_NODE) ? 1.f : 0.f;
                const long off = (long)(id < N_NODE ? id : 0) * DNODE + d0;
                if (MODE) {
                    raw[l].v = *(const bf16x8*)((const __bf16*)featv + off);
                } else {
                    const float4* sp = (const float4*)((const float*)featv + off);
                    rawf[l][0] = sp[0];
                    rawf[l][1] = sp[1];
                }
            }

            float x[8];
#pragma unroll
            for (int i = 0; i < 8; ++i)
                x[i] = MODE ? msk[0] * (float)raw[0].e[i]
                            : msk[0] * ((const float*)&rawf[0][0])[i];
#pragma unroll
            for (int l = 1; l < LPATH; ++l) {
                float y[8];
#pragma unroll
                for (int i = 0; i < 8; ++i)
                    y[i] = MODE ? msk[l] * (float)raw[l].e[i]
                                : msk[l] * ((const float*)&rawf[l][0])[i];
                union { bf16x8 v; __bf16 e[8]; } u;
#pragma unroll
                for (int i = 0; i < 8; ++i) u.e[i] = (__bf16)(x[i] + ew[l - 1] * y[i]);
                *(bf16x8*)(asb + swz(r, (l - 1) * 128 + s * 16)) = u.v;
#pragma unroll
                for (int i = 0; i < 8; ++i) x[i] = y[i];
            }
        }
    }
    __syncthreads();

    // ---------------- MFMA: each wave computes 64 rows x 32 cols ----------
    const int lrow = lane & 15;
    const int h    = lane >> 4;

    f32x4 acc[4][2];
#pragma unroll
    for (int mt = 0; mt < 4; ++mt)
#pragma unroll
        for (int nt = 0; nt < 2; ++nt)
            acc[mt][nt] = (f32x4){0.f, 0.f, 0.f, 0.f};

#pragma unroll
    for (int ks = 0; ks < 10; ++ks) {
#pragma unroll
        for (int mt = 0; mt < 4; ++mt) {
            bf16x8 a = *(const bf16x8*)(asb + swz(mt * 16 + lrow, ks * 64 + h * 16));
            acc[mt][0] = __builtin_amdgcn_mfma_f32_16x16x32_bf16(a, breg[ks][0], acc[mt][0], 0, 0, 0);
            acc[mt][1] = __builtin_amdgcn_mfma_f32_16x16x32_bf16(a, breg[ks][1], acc[mt][1], 0, 0, 0);
        }
    }

    // ---------------- epilogue: nt scalar stores, line-paired order -------
    // For fixed (mt,q) the nt=0 and nt=1 stores cover the SAME 128B line
    // (cols w*32..+15 and +16..+31): issue back-to-back so they merge into
    // full-line writes despite nt.
    const int rbase = h * 4;
#pragma unroll
    for (int mt = 0; mt < 4; ++mt) {
#pragma unroll
        for (int q = 0; q < 4; ++q) {
            long row = p0 + mt * 16 + rbase + q;
            float* rp = &out[row * DPATH + wave * 32 + lrow];
            __builtin_nontemporal_store(acc[mt][0][q], rp);
            __builtin_nontemporal_store(acc[mt][1][q], rp + 16);
        }
    }
}

extern "C" void kernel_launch(void* const* d_in, const int* in_sizes, int n_in,
                              void* d_out, int out_size, void* d_ws, size_t ws_size,
                              hipStream_t stream) {
    const float* feat   = (const float*)d_in[0];
    const float* weight = (const float*)d_in[1];
    const float* W      = (const float*)d_in[2];
    const int*   paths  = (const int*)d_in[3];
    const int*   eids   = (const int*)d_in[4];
    float* out = (float*)d_out;

    char* ws = (char*)d_ws;
    __bf16* wf    = (__bf16*)ws;                                        // 81,920 B
    __bf16* featb = (__bf16*)(ws + WF_BYTES);                           // 6,400,000 B
    __bf16* ewb   = (__bf16*)(ws + WF_BYTES + FEATB_BYTES);             // 3,200,000 B
    __bf16* ewd   = (__bf16*)(ws + WF_BYTES + FEATB_BYTES + EWB_BYTES); // 4,000,000 B

    if (ws_size >= (size_t)WF_BYTES + FEATB_BYTES + EWB_BYTES + EWD_BYTES) {
        fused_prep<<<PREP_BLKS, 256, 0, stream>>>(W, wf, feat, featb, weight, ewb);
        ew_prep<<<(NEW + 255) / 256, 256, 0, stream>>>(ewb, eids, ewd, NEW);
        path_gemm<1><<<NBLK, 256, 0, stream>>>(featb, ewd, paths, eids, wf, out);
    } else {
        fused_prep<<<WF_BLKS, 256, 0, stream>>>(W, wf, feat, featb, weight, ewb);
        path_gemm<0><<<NBLK, 256, 0, stream>>>(feat, weight, paths, eids, wf, out);
    }
}

// Round 11
// 142.478 us; speedup vs baseline: 1.0280x; 1.0280x over previous
//
#include <hip/hip_runtime.h>
#include <hip/hip_bf16.h>

typedef __bf16 bf16x8 __attribute__((ext_vector_type(8)));
typedef float f32x4 __attribute__((ext_vector_type(4)));

#define N_NODE 50000
#define KPATH 8
#define LPATH 6
#define DNODE 64
#define DPATH 128
#define KDIM 320                 // DNODE*(LPATH-1)
#define N_EDGE 1600000
#define NPAIR (N_NODE * KPATH)   // 400000
#define NEW (NPAIR * (LPATH - 1))// 2,000,000 path-edge slots
#define M_BLK 64
#define NBLK (NPAIR / M_BLK)     // 6250
#define ROW_BYTES 640            // 320 bf16 per row, swizzled
#define WF_BYTES 81920
#define FEATB_BYTES (N_NODE * DNODE * 2)
#define EWB_BYTES (N_EDGE * 2)
#define EWD_BYTES (NEW * 2)

// fused-prep block ranges
#define WF_BLKS   160                      // 40960 wf elements
#define FEAT_BLKS 1563                     // 400000 x 8-elem converts
#define WGT_BLKS  782                      // 200000 x 8-elem converts
#define PREP_BLKS (WF_BLKS + FEAT_BLKS + WGT_BLKS)

// XOR-swizzle: 16B unit moved within its 128B group by row. 640 = 5*128 so
// the XOR (max 112) never crosses a row boundary.
__device__ __forceinline__ int swz(int row, int bytecol) {
    return row * ROW_BYTES + (bytecol ^ ((row & 7) << 4));
}

// One launch: W->wf fragment swizzle, feat->bf16, weight->bf16.
__global__ void fused_prep(const float* __restrict__ W, __bf16* __restrict__ wf,
                           const float* __restrict__ feat, __bf16* __restrict__ featb,
                           const float* __restrict__ weight, __bf16* __restrict__ ewb) {
    int b = blockIdx.x;
    if (b < WF_BLKS) {
        int t = b * 256 + threadIdx.x;
        if (t >= 8 * 10 * 64 * 8) return;
        int j    = t & 7;
        int lane = (t >> 3) & 63;
        int ks   = (t >> 9) % 10;
        int nt   = t / 5120;
        int k = ks * 32 + (lane >> 4) * 8 + j;
        int n = nt * 16 + (lane & 15);
        wf[t] = (__bf16)W[n * KDIM + k];
    } else if (b < WF_BLKS + FEAT_BLKS) {
        int t = (b - WF_BLKS) * 256 + threadIdx.x;
        if (t >= N_NODE * DNODE / 8) return;
        float4 a = ((const float4*)feat)[t * 2];
        float4 c = ((const float4*)feat)[t * 2 + 1];
        union { bf16x8 v; __bf16 e[8]; } u;
        u.e[0] = (__bf16)a.x; u.e[1] = (__bf16)a.y; u.e[2] = (__bf16)a.z; u.e[3] = (__bf16)a.w;
        u.e[4] = (__bf16)c.x; u.e[5] = (__bf16)c.y; u.e[6] = (__bf16)c.z; u.e[7] = (__bf16)c.w;
        ((bf16x8*)featb)[t] = u.v;
    } else {
        int t = (b - WF_BLKS - FEAT_BLKS) * 256 + threadIdx.x;
        if (t >= N_EDGE / 8) return;
        float4 a = ((const float4*)weight)[t * 2];
        float4 c = ((const float4*)weight)[t * 2 + 1];
        union { bf16x8 v; __bf16 e[8]; } u;
        u.e[0] = (__bf16)a.x; u.e[1] = (__bf16)a.y; u.e[2] = (__bf16)a.z; u.e[3] = (__bf16)a.w;
        u.e[4] = (__bf16)c.x; u.e[5] = (__bf16)c.y; u.e[6] = (__bf16)c.z; u.e[7] = (__bf16)c.w;
        ((bf16x8*)ewb)[t] = u.v;
    }
}

// Pre-gather edge weights per path slot: ewd[t] = ewb[eids[t]].
// ewb is 3.2 MB bf16 -> fits per-XCD L2, so this random gather is cheap here
// and removes 2M random scalar loads from the hot kernel.
__global__ void ew_prep(const __bf16* __restrict__ ewb, const int* __restrict__ eids,
                        __bf16* __restrict__ ewd, int n) {
    int t = blockIdx.x * 256 + threadIdx.x;
    if (t >= n) return;
    int ev = __builtin_nontemporal_load(eids + t);
    ewd[t] = ewb[ev];
}

// MODE: 1 = feat bf16 + pre-gathered ew bf16 ; 0 = all-f32 inline fallback
template <int MODE>
__global__ __launch_bounds__(256, 4) void path_gemm(
    const void*  __restrict__ featv,
    const void*  __restrict__ wsrc,     // MODE1: ewd (dense bf16); MODE0: weight f32
    const int*   __restrict__ paths,
    const int*   __restrict__ eids,
    const __bf16* __restrict__ wf,
    float* __restrict__ out)
{
    __shared__ bf16x8 AsVec[M_BLK * ROW_BYTES / 16];   // 40,960 B -> 4 blocks/CU
    char* asb = (char*)AsVec;

    const int  t  = threadIdx.x;
    const long p0 = (long)blockIdx.x * M_BLK;
    const int wave = t >> 6;
    const int lane = t & 63;

    // ---- B fragments: load ONCE per block into VGPRs (kills the wf re-read).
    //      Issued first so the L2-hit latency overlaps the gathers below.
    bf16x8 breg[10][2];
#pragma unroll
    for (int ks = 0; ks < 10; ++ks)
#pragma unroll
        for (int nt = 0; nt < 2; ++nt)
            breg[ks][nt] = *(const bf16x8*)(wf + (((wave * 2 + nt) * 10 + ks) * 64 + lane) * 8);

    // ---------------- stage A tile: gather + combine -> bf16 LDS ----------
    // Two passes of the proven 32-row lane-split shape (rows 0-31, 32-63).
    {
        const int  s  = t & 7;           // 16B slice
        const int  d0 = s * 8;
        const int  lr = (t >> 3) & 7;    // row-local index within this wave

#pragma unroll
        for (int pass = 0; pass < 2; ++pass) {
            const int  r = pass * 32 + (t >> 3);     // row 0..63
            const long p = p0 + r;

            // Lane-split scalar loads, broadcast to the row's 8 lanes.
            int pv = 0;
            if (s < LPATH) pv = __builtin_nontemporal_load(paths + p * LPATH + s);
            float wv = 0.f;
            if (s < LPATH - 1) {
                if (MODE) {
                    wv = (float)__builtin_nontemporal_load(
                        (const __bf16*)wsrc + p * (LPATH - 1) + s);
                } else {
                    int ev = __builtin_nontemporal_load(eids + p * (LPATH - 1) + s);
                    wv = ((const float*)wsrc)[ev];
                }
            }

            int idx[LPATH];
#pragma unroll
            for (int l = 0; l < LPATH; ++l) idx[l] = __shfl(pv, lr * 8 + l, 64);
            float ew[LPATH - 1];
#pragma unroll
            for (int l = 0; l < LPATH - 1; ++l) ew[l] = __shfl(wv, lr * 8 + l, 64);

            // Issue ALL 6 row-gathers unconditionally (clamped addr + mask)
            // so the misses overlap instead of serializing 6-deep.
            float msk[LPATH];
            union { bf16x8 v; __bf16 e[8]; } raw[LPATH];
            float4 rawf[LPATH][2];
#pragma unroll
            for (int l = 0; l < LPATH; ++l) {
                const int id = idx[l];
                msk[l] = (id < N_NODE) ? 1.f : 0.f;
                const long off = (long)(id < N_NODE ? id : 0) * DNODE + d0;
                if (MODE) {
                    raw[l].v = *(const bf16x8*)((const __bf16*)featv + off);
                } else {
                    const float4* sp = (const float4*)((const float*)featv + off);
                    rawf[l][0] = sp[0];
                    rawf[l][1] = sp[1];
                }
            }

            float x[8];
#pragma unroll
            for (int i = 0; i < 8; ++i)
                x[i] = MODE ? msk[0] * (float)raw[0].e[i]
                            : msk[0] * ((const float*)&rawf[0][0])[i];
#pragma unroll
            for (int l = 1; l < LPATH; ++l) {
                float y[8];
#pragma unroll
                for (int i = 0; i < 8; ++i)
                    y[i] = MODE ? msk[l] * (float)raw[l].e[i]
                                : msk[l] * ((const float*)&rawf[l][0])[i];
                union { bf16x8 v; __bf16 e[8]; } u;
#pragma unroll
                for (int i = 0; i < 8; ++i) u.e[i] = (__bf16)(x[i] + ew[l - 1] * y[i]);
                *(bf16x8*)(asb + swz(r, (l - 1) * 128 + s * 16)) = u.v;
#pragma unroll
                for (int i = 0; i < 8; ++i) x[i] = y[i];
            }
        }
    }
    __syncthreads();

    // ---------------- MFMA: each wave computes 64 rows x 32 cols ----------
    const int lrow = lane & 15;
    const int h    = lane >> 4;

    f32x4 acc[4][2];
#pragma unroll
    for (int mt = 0; mt < 4; ++mt)
#pragma unroll
        for (int nt = 0; nt < 2; ++nt)
            acc[mt][nt] = (f32x4){0.f, 0.f, 0.f, 0.f};

#pragma unroll
    for (int ks = 0; ks < 10; ++ks) {
#pragma unroll
        for (int mt = 0; mt < 4; ++mt) {
            bf16x8 a = *(const bf16x8*)(asb + swz(mt * 16 + lrow, ks * 64 + h * 16));
            acc[mt][0] = __builtin_amdgcn_mfma_f32_16x16x32_bf16(a, breg[ks][0], acc[mt][0], 0, 0, 0);
            acc[mt][1] = __builtin_amdgcn_mfma_f32_16x16x32_bf16(a, breg[ks][1], acc[mt][1], 0, 0, 0);
        }
    }

    // ---------------- epilogue: PLAIN cached stores, line-paired order ----
    // nt stores bypass L2 and issue 64B half-lines to HBM (write amplification
    // 200->302 MB measured in R10). Plain stores merge in L2 and write back
    // exactly one 128B line per output line: WRITE == 200 MB.
    const int rbase = h * 4;
#pragma unroll
    for (int mt = 0; mt < 4; ++mt) {
#pragma unroll
        for (int q = 0; q < 4; ++q) {
            long row = p0 + mt * 16 + rbase + q;
            float* rp = &out[row * DPATH + wave * 32 + lrow];
            rp[0]  = acc[mt][0][q];
            rp[16] = acc[mt][1][q];
        }
    }
}

extern "C" void kernel_launch(void* const* d_in, const int* in_sizes, int n_in,
                              void* d_out, int out_size, void* d_ws, size_t ws_size,
                              hipStream_t stream) {
    const float* feat   = (const float*)d_in[0];
    const float* weight = (const float*)d_in[1];
    const float* W      = (const float*)d_in[2];
    const int*   paths  = (const int*)d_in[3];
    const int*   eids   = (const int*)d_in[4];
    float* out = (float*)d_out;

    char* ws = (char*)d_ws;
    __bf16* wf    = (__bf16*)ws;                                        // 81,920 B
    __bf16* featb = (__bf16*)(ws + WF_BYTES);                           // 6,400,000 B
    __bf16* ewb   = (__bf16*)(ws + WF_BYTES + FEATB_BYTES);             // 3,200,000 B
    __bf16* ewd   = (__bf16*)(ws + WF_BYTES + FEATB_BYTES + EWB_BYTES); // 4,000,000 B

    if (ws_size >= (size_t)WF_BYTES + FEATB_BYTES + EWB_BYTES + EWD_BYTES) {
        fused_prep<<<PREP_BLKS, 256, 0, stream>>>(W, wf, feat, featb, weight, ewb);
        ew_prep<<<(NEW + 255) / 256, 256, 0, stream>>>(ewb, eids, ewd, NEW);
        path_gemm<1><<<NBLK, 256, 0, stream>>>(featb, ewd, paths, eids, wf, out);
    } else {
        fused_prep<<<WF_BLKS, 256, 0, stream>>>(W, wf, feat, featb, weight, ewb);
        path_gemm<0><<<NBLK, 256, 0, stream>>>(feat, weight, paths, eids, wf, out);
    }
}

// Round 12
// 130.697 us; speedup vs baseline: 1.1206x; 1.0901x over previous
//
#include <hip/hip_runtime.h>
#include <hip/hip_bf16.h>

typedef __bf16 bf16x8 __attribute__((ext_vector_type(8)));
typedef float f32x4 __attribute__((ext_vector_type(4)));

#define N_NODE 50000
#define KPATH 8
#define LPATH 6
#define DNODE 64
#define DPATH 128
#define KDIM 320                 // DNODE*(LPATH-1)
#define N_EDGE 1600000
#define NPAIR (N_NODE * KPATH)   // 400000
#define M_BLK 64
#define NBLK (NPAIR / M_BLK)     // 6250
#define ROW_BYTES 640            // 320 bf16 per row, swizzled
#define WF_BYTES 81920
#define FEATB_BYTES (N_NODE * DNODE * 2)
#define EWB_BYTES (N_EDGE * 2)

// fused-prep block ranges
#define WF_BLKS   160                      // 40960 wf elements
#define FEAT_BLKS 1563                     // 400000 x 8-elem converts
#define WGT_BLKS  782                      // 200000 x 8-elem converts
#define PREP_BLKS (WF_BLKS + FEAT_BLKS + WGT_BLKS)

// XOR-swizzle: 16B unit moved within its 128B group by row. 640 = 5*128 so
// the XOR (max 112) never crosses a row boundary.
__device__ __forceinline__ int swz(int row, int bytecol) {
    return row * ROW_BYTES + (bytecol ^ ((row & 7) << 4));
}

// One launch: W->wf fragment swizzle, feat->bf16, weight->bf16.
__global__ void fused_prep(const float* __restrict__ W, __bf16* __restrict__ wf,
                           const float* __restrict__ feat, __bf16* __restrict__ featb,
                           const float* __restrict__ weight, __bf16* __restrict__ ewb) {
    int b = blockIdx.x;
    if (b < WF_BLKS) {
        int t = b * 256 + threadIdx.x;
        if (t >= 8 * 10 * 64 * 8) return;
        int j    = t & 7;
        int lane = (t >> 3) & 63;
        int ks   = (t >> 9) % 10;
        int nt   = t / 5120;
        int k = ks * 32 + (lane >> 4) * 8 + j;
        int n = nt * 16 + (lane & 15);
        wf[t] = (__bf16)W[n * KDIM + k];
    } else if (b < WF_BLKS + FEAT_BLKS) {
        int t = (b - WF_BLKS) * 256 + threadIdx.x;
        if (t >= N_NODE * DNODE / 8) return;
        float4 a = ((const float4*)feat)[t * 2];
        float4 c = ((const float4*)feat)[t * 2 + 1];
        union { bf16x8 v; __bf16 e[8]; } u;
        u.e[0] = (__bf16)a.x; u.e[1] = (__bf16)a.y; u.e[2] = (__bf16)a.z; u.e[3] = (__bf16)a.w;
        u.e[4] = (__bf16)c.x; u.e[5] = (__bf16)c.y; u.e[6] = (__bf16)c.z; u.e[7] = (__bf16)c.w;
        ((bf16x8*)featb)[t] = u.v;
    } else {
        int t = (b - WF_BLKS - FEAT_BLKS) * 256 + threadIdx.x;
        if (t >= N_EDGE / 8) return;
        float4 a = ((const float4*)weight)[t * 2];
        float4 c = ((const float4*)weight)[t * 2 + 1];
        union { bf16x8 v; __bf16 e[8]; } u;
        u.e[0] = (__bf16)a.x; u.e[1] = (__bf16)a.y; u.e[2] = (__bf16)a.z; u.e[3] = (__bf16)a.w;
        u.e[4] = (__bf16)c.x; u.e[5] = (__bf16)c.y; u.e[6] = (__bf16)c.z; u.e[7] = (__bf16)c.w;
        ((bf16x8*)ewb)[t] = u.v;
    }
}

// MODE: 1 = feat bf16 + weight bf16 ; 0 = all-f32 inline fallback
template <int MODE>
__global__ __launch_bounds__(256) void path_gemm(
    const void*  __restrict__ featv,
    const void*  __restrict__ weightv,
    const int*   __restrict__ paths,
    const int*   __restrict__ eids,
    const __bf16* __restrict__ wf,
    float* __restrict__ out)
{
    __shared__ bf16x8 AsVec[M_BLK * ROW_BYTES / 16];   // 40,960 B
    char* asb = (char*)AsVec;

    const int  t  = threadIdx.x;
    const long p0 = (long)blockIdx.x * M_BLK;
    const int wave = t >> 6;
    const int lane = t & 63;

    // ---- B fragments: load ONCE per block into VGPRs (kills the wf re-read).
    //      Issued first so the L2-hit latency overlaps the gathers below.
    bf16x8 breg[10][2];
#pragma unroll
    for (int ks = 0; ks < 10; ++ks)
#pragma unroll
        for (int nt = 0; nt < 2; ++nt)
            breg[ks][nt] = *(const bf16x8*)(wf + (((wave * 2 + nt) * 10 + ks) * 64 + lane) * 8);

    // ---------------- stage A tile: gather + combine -> bf16 LDS ----------
    // Two passes of the proven 32-row lane-split shape (rows 0-31, 32-63).
    {
        const int  s  = t & 7;           // 16B slice
        const int  d0 = s * 8;
        const int  lr = (t >> 3) & 7;    // row-local index within this wave

#pragma unroll
        for (int pass = 0; pass < 2; ++pass) {
            const int  r = pass * 32 + (t >> 3);     // row 0..63
            const long p = p0 + r;

            // Lane-split scalar loads, broadcast to the row's 8 lanes.
            int pv = 0;
            if (s < LPATH) pv = __builtin_nontemporal_load(paths + p * LPATH + s);
            float wv = 0.f;
            if (s < LPATH - 1) {
                int ev = __builtin_nontemporal_load(eids + p * (LPATH - 1) + s);
                wv = MODE ? (float)((const __bf16*)weightv)[ev]
                          : ((const float*)weightv)[ev];
            }

            int idx[LPATH];
#pragma unroll
            for (int l = 0; l < LPATH; ++l) idx[l] = __shfl(pv, lr * 8 + l, 64);
            float ew[LPATH - 1];
#pragma unroll
            for (int l = 0; l < LPATH - 1; ++l) ew[l] = __shfl(wv, lr * 8 + l, 64);

            // Issue ALL 6 row-gathers unconditionally (clamped addr + mask)
            // so the misses overlap instead of serializing 6-deep.
            float msk[LPATH];
            union { bf16x8 v; __bf16 e[8]; } raw[LPATH];
            float4 rawf[LPATH][2];
#pragma unroll
            for (int l = 0; l < LPATH; ++l) {
                const int id = idx[l];
                msk[l] = (id < N_NODE) ? 1.f : 0.f;
                const long off = (long)(id < N_NODE ? id : 0) * DNODE + d0;
                if (MODE) {
                    raw[l].v = *(const bf16x8*)((const __bf16*)featv + off);
                } else {
                    const float4* sp = (const float4*)((const float*)featv + off);
                    rawf[l][0] = sp[0];
                    rawf[l][1] = sp[1];
                }
            }

            float x[8];
#pragma unroll
            for (int i = 0; i < 8; ++i)
                x[i] = MODE ? msk[0] * (float)raw[0].e[i]
                            : msk[0] * ((const float*)&rawf[0][0])[i];
#pragma unroll
            for (int l = 1; l < LPATH; ++l) {
                float y[8];
#pragma unroll
                for (int i = 0; i < 8; ++i)
                    y[i] = MODE ? msk[l] * (float)raw[l].e[i]
                                : msk[l] * ((const float*)&rawf[l][0])[i];
                union { bf16x8 v; __bf16 e[8]; } u;
#pragma unroll
                for (int i = 0; i < 8; ++i) u.e[i] = (__bf16)(x[i] + ew[l - 1] * y[i]);
                *(bf16x8*)(asb + swz(r, (l - 1) * 128 + s * 16)) = u.v;
#pragma unroll
                for (int i = 0; i < 8; ++i) x[i] = y[i];
            }
        }
    }
    __syncthreads();

    // ---------------- MFMA: each wave computes 64 rows x 32 cols ----------
    const int lrow = lane & 15;
    const int h    = lane >> 4;

    f32x4 acc[4][2];
#pragma unroll
    for (int mt = 0; mt < 4; ++mt)
#pragma unroll
        for (int nt = 0; nt < 2; ++nt)
            acc[mt][nt] = (f32x4){0.f, 0.f, 0.f, 0.f};

#pragma unroll
    for (int ks = 0; ks < 10; ++ks) {
#pragma unroll
        for (int mt = 0; mt < 4; ++mt) {
            bf16x8 a = *(const bf16x8*)(asb + swz(mt * 16 + lrow, ks * 64 + h * 16));
            acc[mt][0] = __builtin_amdgcn_mfma_f32_16x16x32_bf16(a, breg[ks][0], acc[mt][0], 0, 0, 0);
            acc[mt][1] = __builtin_amdgcn_mfma_f32_16x16x32_bf16(a, breg[ks][1], acc[mt][1], 0, 0, 0);
        }
    }

    // ---------------- epilogue: R1/R3-verified order, plain cached stores --
    // The ONLY epilogues that measured WRITE == 200 MB (no amplification)
    // are this mt -> nt -> q scalar order (R1: M64, R3: M32). Pair-adjacent
    // and float4-transposed variants measured 275-302 MB. Keep it exactly.
    const int rbase = h * 4;
#pragma unroll
    for (int mt = 0; mt < 4; ++mt) {
#pragma unroll
        for (int nt = 0; nt < 2; ++nt) {
#pragma unroll
            for (int q = 0; q < 4; ++q) {
                long row = p0 + mt * 16 + rbase + q;
                int  col = wave * 32 + nt * 16 + lrow;
                out[row * DPATH + col] = acc[mt][nt][q];
            }
        }
    }
}

extern "C" void kernel_launch(void* const* d_in, const int* in_sizes, int n_in,
                              void* d_out, int out_size, void* d_ws, size_t ws_size,
                              hipStream_t stream) {
    const float* feat   = (const float*)d_in[0];
    const float* weight = (const float*)d_in[1];
    const float* W      = (const float*)d_in[2];
    const int*   paths  = (const int*)d_in[3];
    const int*   eids   = (const int*)d_in[4];
    float* out = (float*)d_out;

    char* ws = (char*)d_ws;
    __bf16* wf    = (__bf16*)ws;                                   // 81,920 B
    __bf16* featb = (__bf16*)(ws + WF_BYTES);                      // 6,400,000 B
    __bf16* ewb   = (__bf16*)(ws + WF_BYTES + FEATB_BYTES);        // 3,200,000 B

    if (ws_size >= (size_t)WF_BYTES + FEATB_BYTES + EWB_BYTES) {
        fused_prep<<<PREP_BLKS, 256, 0, stream>>>(W, wf, feat, featb, weight, ewb);
        path_gemm<1><<<NBLK, 256, 0, stream>>>(featb, ewb, paths, eids, wf, out);
    } else {
        fused_prep<<<WF_BLKS, 256, 0, stream>>>(W, wf, feat, featb, weight, ewb);
        path_gemm<0><<<NBLK, 256, 0, stream>>>(feat, weight, paths, eids, wf, out);
    }
}

// Round 13
// 116.791 us; speedup vs baseline: 1.2541x; 1.1191x over previous
//
#include <hip/hip_runtime.h>
#include <hip/hip_bf16.h>

typedef __bf16 bf16x8 __attribute__((ext_vector_type(8)));
typedef float f32x4 __attribute__((ext_vector_type(4)));

#define N_NODE 50000
#define KPATH 8
#define LPATH 6
#define DNODE 64
#define DPATH 128
#define KDIM 320                 // DNODE*(LPATH-1)
#define N_EDGE 1600000
#define NPAIR (N_NODE * KPATH)   // 400000
#define M_BLK 32
#define NBLK (NPAIR / M_BLK)     // 12500
#define ROW_BYTES 640            // 320 bf16 per row, swizzled
#define WF_BYTES 81920
#define FEATB_BYTES (N_NODE * DNODE * 2)
#define EWB_BYTES (N_EDGE * 2)

// fused-prep block ranges
#define WF_BLKS   160                      // 40960 wf elements
#define FEAT_BLKS 1563                     // 400000 x 8-elem converts
#define WGT_BLKS  782                      // 200000 x 8-elem converts
#define PREP_BLKS (WF_BLKS + FEAT_BLKS + WGT_BLKS)

// XOR-swizzle: 16B unit moved within its 128B group by row. 640 = 5*128 so
// the XOR (max 112) never crosses a row boundary.
__device__ __forceinline__ int swz(int row, int bytecol) {
    return row * ROW_BYTES + (bytecol ^ ((row & 7) << 4));
}

// One launch: W->wf fragment swizzle, feat->bf16, weight->bf16.
__global__ void fused_prep(const float* __restrict__ W, __bf16* __restrict__ wf,
                           const float* __restrict__ feat, __bf16* __restrict__ featb,
                           const float* __restrict__ weight, __bf16* __restrict__ ewb) {
    int b = blockIdx.x;
    if (b < WF_BLKS) {
        int t = b * 256 + threadIdx.x;
        if (t >= 8 * 10 * 64 * 8) return;
        int j    = t & 7;
        int lane = (t >> 3) & 63;
        int ks   = (t >> 9) % 10;
        int nt   = t / 5120;
        int k = ks * 32 + (lane >> 4) * 8 + j;
        int n = nt * 16 + (lane & 15);
        wf[t] = (__bf16)W[n * KDIM + k];
    } else if (b < WF_BLKS + FEAT_BLKS) {
        int t = (b - WF_BLKS) * 256 + threadIdx.x;
        if (t >= N_NODE * DNODE / 8) return;
        float4 a = ((const float4*)feat)[t * 2];
        float4 c = ((const float4*)feat)[t * 2 + 1];
        union { bf16x8 v; __bf16 e[8]; } u;
        u.e[0] = (__bf16)a.x; u.e[1] = (__bf16)a.y; u.e[2] = (__bf16)a.z; u.e[3] = (__bf16)a.w;
        u.e[4] = (__bf16)c.x; u.e[5] = (__bf16)c.y; u.e[6] = (__bf16)c.z; u.e[7] = (__bf16)c.w;
        ((bf16x8*)featb)[t] = u.v;
    } else {
        int t = (b - WF_BLKS - FEAT_BLKS) * 256 + threadIdx.x;
        if (t >= N_EDGE / 8) return;
        float4 a = ((const float4*)weight)[t * 2];
        float4 c = ((const float4*)weight)[t * 2 + 1];
        union { bf16x8 v; __bf16 e[8]; } u;
        u.e[0] = (__bf16)a.x; u.e[1] = (__bf16)a.y; u.e[2] = (__bf16)a.z; u.e[3] = (__bf16)a.w;
        u.e[4] = (__bf16)c.x; u.e[5] = (__bf16)c.y; u.e[6] = (__bf16)c.z; u.e[7] = (__bf16)c.w;
        ((bf16x8*)ewb)[t] = u.v;
    }
}

// MODE: 1 = feat bf16 + weight bf16 ; 0 = all-f32 inline fallback
template <int MODE>
__global__ __launch_bounds__(256) void path_gemm(
    const void*  __restrict__ featv,
    const void*  __restrict__ weightv,
    const int*   __restrict__ paths,
    const int*   __restrict__ eids,
    const __bf16* __restrict__ wf,
    float* __restrict__ out)
{
    __shared__ bf16x8 AsVec[M_BLK * ROW_BYTES / 16];   // 20,480 B -> 8 blocks/CU
    char* asb = (char*)AsVec;

    const int  t  = threadIdx.x;
    const long p0 = (long)blockIdx.x * M_BLK;
    const int wave = t >> 6;
    const int lane = t & 63;

    // ---- B fragments: load ONCE per block into VGPRs (kills the wf re-read).
    //      Issued first so the L2-hit latency overlaps the gathers below.
    bf16x8 breg[10][2];
#pragma unroll
    for (int ks = 0; ks < 10; ++ks)
#pragma unroll
        for (int nt = 0; nt < 2; ++nt)
            breg[ks][nt] = *(const bf16x8*)(wf + (((wave * 2 + nt) * 10 + ks) * 64 + lane) * 8);

    // ---------------- stage A tile: gather + combine -> bf16 LDS ----------
    {
        const int  r  = t >> 3;          // row 0..31
        const int  s  = t & 7;           // 16B slice
        const int  d0 = s * 8;
        const int  lr = r & 7;           // row-local index within this wave
        const long p  = p0 + r;

        // Lane-split scalar loads, broadcast to the row's 8 lanes.
        int pv = 0;
        if (s < LPATH) pv = __builtin_nontemporal_load(paths + p * LPATH + s);
        float wv = 0.f;
        if (s < LPATH - 1) {
            int ev = __builtin_nontemporal_load(eids + p * (LPATH - 1) + s);
            wv = MODE ? (float)((const __bf16*)weightv)[ev]
                      : ((const float*)weightv)[ev];
        }

        int idx[LPATH];
#pragma unroll
        for (int l = 0; l < LPATH; ++l) idx[l] = __shfl(pv, lr * 8 + l, 64);
        float ew[LPATH - 1];
#pragma unroll
        for (int l = 0; l < LPATH - 1; ++l) ew[l] = __shfl(wv, lr * 8 + l, 64);

        // Issue ALL 6 row-gathers unconditionally (clamped addr + mask) so
        // the misses overlap instead of serializing 6-deep.
        float msk[LPATH];
        union { bf16x8 v; __bf16 e[8]; } raw[LPATH];
        float4 rawf[LPATH][2];
#pragma unroll
        for (int l = 0; l < LPATH; ++l) {
            const int id = idx[l];
            msk[l] = (id < N_NODE) ? 1.f : 0.f;
            const long off = (long)(id < N_NODE ? id : 0) * DNODE + d0;
            if (MODE) {
                raw[l].v = *(const bf16x8*)((const __bf16*)featv + off);
            } else {
                const float4* sp = (const float4*)((const float*)featv + off);
                rawf[l][0] = sp[0];
                rawf[l][1] = sp[1];
            }
        }

        float x[8];
#pragma unroll
        for (int i = 0; i < 8; ++i)
            x[i] = MODE ? msk[0] * (float)raw[0].e[i]
                        : msk[0] * ((const float*)&rawf[0][0])[i];
#pragma unroll
        for (int l = 1; l < LPATH; ++l) {
            float y[8];
#pragma unroll
            for (int i = 0; i < 8; ++i)
                y[i] = MODE ? msk[l] * (float)raw[l].e[i]
                            : msk[l] * ((const float*)&rawf[l][0])[i];
            union { bf16x8 v; __bf16 e[8]; } u;
#pragma unroll
            for (int i = 0; i < 8; ++i) u.e[i] = (__bf16)(x[i] + ew[l - 1] * y[i]);
            *(bf16x8*)(asb + swz(r, (l - 1) * 128 + s * 16)) = u.v;
#pragma unroll
            for (int i = 0; i < 8; ++i) x[i] = y[i];
        }
    }
    __syncthreads();

    // ---------------- MFMA: each wave computes 32 rows x 32 cols ----------
    const int lrow = lane & 15;
    const int h    = lane >> 4;

    f32x4 acc[2][2];
#pragma unroll
    for (int mt = 0; mt < 2; ++mt)
#pragma unroll
        for (int nt = 0; nt < 2; ++nt)
            acc[mt][nt] = (f32x4){0.f, 0.f, 0.f, 0.f};

#pragma unroll
    for (int ks = 0; ks < 10; ++ks) {
#pragma unroll
        for (int mt = 0; mt < 2; ++mt) {
            bf16x8 a = *(const bf16x8*)(asb + swz(mt * 16 + lrow, ks * 64 + h * 16));
            acc[mt][0] = __builtin_amdgcn_mfma_f32_16x16x32_bf16(a, breg[ks][0], acc[mt][0], 0, 0, 0);
            acc[mt][1] = __builtin_amdgcn_mfma_f32_16x16x32_bf16(a, breg[ks][1], acc[mt][1], 0, 0, 0);
        }
    }

    // ---------------- epilogue: R1/R3/R12-verified order, plain stores ----
    // mt -> nt -> q scalar plain stores measured WRITE == 200 MB exactly
    // (R1 M64, R3 M32, R12 M64). All paired / transposed / nt variants
    // measured 275-302 MB. Keep this exact order.
    const int rbase = h * 4;
#pragma unroll
    for (int mt = 0; mt < 2; ++mt) {
#pragma unroll
        for (int nt = 0; nt < 2; ++nt) {
#pragma unroll
            for (int q = 0; q < 4; ++q) {
                long row = p0 + mt * 16 + rbase + q;
                int  col = wave * 32 + nt * 16 + lrow;
                out[row * DPATH + col] = acc[mt][nt][q];
            }
        }
    }
}

extern "C" void kernel_launch(void* const* d_in, const int* in_sizes, int n_in,
                              void* d_out, int out_size, void* d_ws, size_t ws_size,
                              hipStream_t stream) {
    const float* feat   = (const float*)d_in[0];
    const float* weight = (const float*)d_in[1];
    const float* W      = (const float*)d_in[2];
    const int*   paths  = (const int*)d_in[3];
    const int*   eids   = (const int*)d_in[4];
    float* out = (float*)d_out;

    char* ws = (char*)d_ws;
    __bf16* wf    = (__bf16*)ws;                                   // 81,920 B
    __bf16* featb = (__bf16*)(ws + WF_BYTES);                      // 6,400,000 B
    __bf16* ewb   = (__bf16*)(ws + WF_BYTES + FEATB_BYTES);        // 3,200,000 B

    if (ws_size >= (size_t)WF_BYTES + FEATB_BYTES + EWB_BYTES) {
        fused_prep<<<PREP_BLKS, 256, 0, stream>>>(W, wf, feat, featb, weight, ewb);
        path_gemm<1><<<NBLK, 256, 0, stream>>>(featb, ewb, paths, eids, wf, out);
    } else {
        fused_prep<<<WF_BLKS, 256, 0, stream>>>(W, wf, feat, featb, weight, ewb);
        path_gemm<0><<<NBLK, 256, 0, stream>>>(feat, weight, paths, eids, wf, out);
    }
}

// Round 14
// 114.466 us; speedup vs baseline: 1.2795x; 1.0203x over previous
//
#include <hip/hip_runtime.h>
#include <hip/hip_bf16.h>

typedef __bf16 bf16x8 __attribute__((ext_vector_type(8)));
typedef float f32x4 __attribute__((ext_vector_type(4)));

#define N_NODE 50000
#define KPATH 8
#define LPATH 6
#define DNODE 64
#define DPATH 128
#define KDIM 320                 // DNODE*(LPATH-1)
#define N_EDGE 1600000
#define NPAIR (N_NODE * KPATH)   // 400000
#define M_BLK 32
#define NBLK (NPAIR / M_BLK)     // 12500
#define ROW_BYTES 640            // 320 bf16 per row, swizzled
#define WF_BYTES 81920
#define FEATB_BYTES (N_NODE * DNODE * 2)
#define EWB_BYTES (N_EDGE * 2)

// fused-prep block ranges
#define WF_BLKS   160                      // 40960 wf elements
#define FEAT_BLKS 1563                     // 400000 x 8-elem converts
#define WGT_BLKS  782                      // 200000 x 8-elem converts
#define PREP_BLKS (WF_BLKS + FEAT_BLKS + WGT_BLKS)

// XOR-swizzle: 16B unit moved within its 128B group by row. 640 = 5*128 so
// the XOR (max 112) never crosses a row boundary.
__device__ __forceinline__ int swz(int row, int bytecol) {
    return row * ROW_BYTES + (bytecol ^ ((row & 7) << 4));
}

// One launch: W->wf fragment swizzle, feat->bf16, weight->bf16.
__global__ void fused_prep(const float* __restrict__ W, __bf16* __restrict__ wf,
                           const float* __restrict__ feat, __bf16* __restrict__ featb,
                           const float* __restrict__ weight, __bf16* __restrict__ ewb) {
    int b = blockIdx.x;
    if (b < WF_BLKS) {
        int t = b * 256 + threadIdx.x;
        if (t >= 8 * 10 * 64 * 8) return;
        int j    = t & 7;
        int lane = (t >> 3) & 63;
        int ks   = (t >> 9) % 10;
        int nt   = t / 5120;
        int k = ks * 32 + (lane >> 4) * 8 + j;
        int n = nt * 16 + (lane & 15);
        wf[t] = (__bf16)W[n * KDIM + k];
    } else if (b < WF_BLKS + FEAT_BLKS) {
        int t = (b - WF_BLKS) * 256 + threadIdx.x;
        if (t >= N_NODE * DNODE / 8) return;
        float4 a = ((const float4*)feat)[t * 2];
        float4 c = ((const float4*)feat)[t * 2 + 1];
        union { bf16x8 v; __bf16 e[8]; } u;
        u.e[0] = (__bf16)a.x; u.e[1] = (__bf16)a.y; u.e[2] = (__bf16)a.z; u.e[3] = (__bf16)a.w;
        u.e[4] = (__bf16)c.x; u.e[5] = (__bf16)c.y; u.e[6] = (__bf16)c.z; u.e[7] = (__bf16)c.w;
        ((bf16x8*)featb)[t] = u.v;
    } else {
        int t = (b - WF_BLKS - FEAT_BLKS) * 256 + threadIdx.x;
        if (t >= N_EDGE / 8) return;
        float4 a = ((const float4*)weight)[t * 2];
        float4 c = ((const float4*)weight)[t * 2 + 1];
        union { bf16x8 v; __bf16 e[8]; } u;
        u.e[0] = (__bf16)a.x; u.e[1] = (__bf16)a.y; u.e[2] = (__bf16)a.z; u.e[3] = (__bf16)a.w;
        u.e[4] = (__bf16)c.x; u.e[5] = (__bf16)c.y; u.e[6] = (__bf16)c.z; u.e[7] = (__bf16)c.w;
        ((bf16x8*)ewb)[t] = u.v;
    }
}

// MODE: 1 = feat bf16 + weight bf16 ; 0 = all-f32 inline fallback
template <int MODE>
__global__ __launch_bounds__(256) void path_gemm(
    const void*  __restrict__ featv,
    const void*  __restrict__ weightv,
    const int*   __restrict__ paths,
    const int*   __restrict__ eids,
    const __bf16* __restrict__ wf,
    float* __restrict__ out)
{
    __shared__ bf16x8 AsVec[M_BLK * ROW_BYTES / 16];   // 20,480 B -> 8 blocks/CU
    char* asb = (char*)AsVec;

    const int  t  = threadIdx.x;
    const long p0 = (long)blockIdx.x * M_BLK;
    const int wave = t >> 6;
    const int lane = t & 63;

    // ---- B fragments: load ONCE per block into VGPRs (kills the wf re-read).
    //      Issued first so the L2-hit latency overlaps the gathers below.
    bf16x8 breg[10][2];
#pragma unroll
    for (int ks = 0; ks < 10; ++ks)
#pragma unroll
        for (int nt = 0; nt < 2; ++nt)
            breg[ks][nt] = *(const bf16x8*)(wf + (((wave * 2 + nt) * 10 + ks) * 64 + lane) * 8);

    // ---------------- stage A tile: gather + combine -> bf16 LDS ----------
    {
        const int  r  = t >> 3;          // row 0..31
        const int  s  = t & 7;           // 16B slice
        const int  d0 = s * 8;
        const int  lr = r & 7;           // row-local index within this wave
        const long p  = p0 + r;

        // Lane-split scalar loads, broadcast to the row's 8 lanes.
        int pv = 0;
        if (s < LPATH) pv = __builtin_nontemporal_load(paths + p * LPATH + s);
        float wv = 0.f;
        if (s < LPATH - 1) {
            int ev = __builtin_nontemporal_load(eids + p * (LPATH - 1) + s);
            wv = MODE ? (float)((const __bf16*)weightv)[ev]
                      : ((const float*)weightv)[ev];
        }

        int idx[LPATH];
#pragma unroll
        for (int l = 0; l < LPATH; ++l) idx[l] = __shfl(pv, lr * 8 + l, 64);
        float ew[LPATH - 1];
#pragma unroll
        for (int l = 0; l < LPATH - 1; ++l) ew[l] = __shfl(wv, lr * 8 + l, 64);

        // Issue ALL 6 row-gathers unconditionally (clamped addr + mask) so
        // the misses overlap instead of serializing 6-deep.
        float msk[LPATH];
        union { bf16x8 v; __bf16 e[8]; } raw[LPATH];
        float4 rawf[LPATH][2];
#pragma unroll
        for (int l = 0; l < LPATH; ++l) {
            const int id = idx[l];
            msk[l] = (id < N_NODE) ? 1.f : 0.f;
            const long off = (long)(id < N_NODE ? id : 0) * DNODE + d0;
            if (MODE) {
                raw[l].v = *(const bf16x8*)((const __bf16*)featv + off);
            } else {
                const float4* sp = (const float4*)((const float*)featv + off);
                rawf[l][0] = sp[0];
                rawf[l][1] = sp[1];
            }
        }

        float x[8];
#pragma unroll
        for (int i = 0; i < 8; ++i)
            x[i] = MODE ? msk[0] * (float)raw[0].e[i]
                        : msk[0] * ((const float*)&rawf[0][0])[i];
#pragma unroll
        for (int l = 1; l < LPATH; ++l) {
            float y[8];
#pragma unroll
            for (int i = 0; i < 8; ++i)
                y[i] = MODE ? msk[l] * (float)raw[l].e[i]
                            : msk[l] * ((const float*)&rawf[l][0])[i];
            union { bf16x8 v; __bf16 e[8]; } u;
#pragma unroll
            for (int i = 0; i < 8; ++i) u.e[i] = (__bf16)(x[i] + ew[l - 1] * y[i]);
            *(bf16x8*)(asb + swz(r, (l - 1) * 128 + s * 16)) = u.v;
#pragma unroll
            for (int i = 0; i < 8; ++i) x[i] = y[i];
        }
    }
    __syncthreads();

    // ---------------- MFMA: each wave computes 32 rows x 32 cols ----------
    const int lrow = lane & 15;
    const int h    = lane >> 4;

    f32x4 acc[2][2];
#pragma unroll
    for (int mt = 0; mt < 2; ++mt)
#pragma unroll
        for (int nt = 0; nt < 2; ++nt)
            acc[mt][nt] = (f32x4){0.f, 0.f, 0.f, 0.f};

#pragma unroll
    for (int ks = 0; ks < 10; ++ks) {
#pragma unroll
        for (int mt = 0; mt < 2; ++mt) {
            bf16x8 a = *(const bf16x8*)(asb + swz(mt * 16 + lrow, ks * 64 + h * 16));
            acc[mt][0] = __builtin_amdgcn_mfma_f32_16x16x32_bf16(a, breg[ks][0], acc[mt][0], 0, 0, 0);
            acc[mt][1] = __builtin_amdgcn_mfma_f32_16x16x32_bf16(a, breg[ks][1], acc[mt][1], 0, 0, 0);
        }
    }

    // ---------------- epilogue: LDS transpose -> FULL-LINE nt stores ------
    // R10 vs R12 A/B: plain scalar stores cost +30 MB FETCH (RFO/L2
    // pollution); nt at 64B half-line granularity cost +100 MB WRITE (no
    // cross-instruction merge). Fix: transpose each wave's 16x32 f32 tile
    // through wave-private LDS so ONE store instruction covers 8 complete
    // 128B lines (8 lanes x f32x4 = one full line) -> nt with no
    // amplification and no RFO.
    __syncthreads();                       // all waves done reading As
    {
        char* sc = asb + wave * 2048;      // wave-private 2KB scratch in As
        const int r8 = lane >> 3;          // 0..7
        const int c4 = lane & 7;           // 0..7
#pragma unroll
        for (int mt = 0; mt < 2; ++mt) {
            // scatter acc into [16 rows][8 units of 16B], unit XOR-swizzled
            // by row (2-way banks max on both sides)
#pragma unroll
            for (int nt = 0; nt < 2; ++nt) {
#pragma unroll
                for (int q = 0; q < 4; ++q) {
                    int row  = h * 4 + q;                  // 0..15
                    int colq = nt * 4 + (lrow >> 2);       // 0..7
                    *(float*)(sc + row * 128 + ((colq ^ (row & 7)) << 4)
                              + ((lrow & 3) << 2)) = acc[mt][nt][q];
                }
            }
            // gather rows: lane holds cols 4*c4..+3 of row i*8+r8
#pragma unroll
            for (int i = 0; i < 2; ++i) {
                int row = i * 8 + r8;
                f32x4 v = *(f32x4*)(sc + row * 128 + (((c4 ^ (row & 7))) << 4));
                long grow = p0 + mt * 16 + row;
                __builtin_nontemporal_store(
                    v, (f32x4*)&out[grow * DPATH + wave * 32 + c4 * 4]);
            }
        }
    }
}

extern "C" void kernel_launch(void* const* d_in, const int* in_sizes, int n_in,
                              void* d_out, int out_size, void* d_ws, size_t ws_size,
                              hipStream_t stream) {
    const float* feat   = (const float*)d_in[0];
    const float* weight = (const float*)d_in[1];
    const float* W      = (const float*)d_in[2];
    const int*   paths  = (const int*)d_in[3];
    const int*   eids   = (const int*)d_in[4];
    float* out = (float*)d_out;

    char* ws = (char*)d_ws;
    __bf16* wf    = (__bf16*)ws;                                   // 81,920 B
    __bf16* featb = (__bf16*)(ws + WF_BYTES);                      // 6,400,000 B
    __bf16* ewb   = (__bf16*)(ws + WF_BYTES + FEATB_BYTES);        // 3,200,000 B

    if (ws_size >= (size_t)WF_BYTES + FEATB_BYTES + EWB_BYTES) {
        fused_prep<<<PREP_BLKS, 256, 0, stream>>>(W, wf, feat, featb, weight, ewb);
        path_gemm<1><<<NBLK, 256, 0, stream>>>(featb, ewb, paths, eids, wf, out);
    } else {
        fused_prep<<<WF_BLKS, 256, 0, stream>>>(W, wf, feat, featb, weight, ewb);
        path_gemm<0><<<NBLK, 256, 0, stream>>>(feat, weight, paths, eids, wf, out);
    }
}